// Round 1
// baseline (308.140 us; speedup 1.0000x reference)
//
#include <hip/hip_runtime.h>

// Problem constants
#define NB 2        // batch
#define NPTS 1024   // D_IN points per cloud
#define NGEN 65536  // G * D_IN generated points
#define NG 64       // grid points

// ws layout (float offsets). Total 609921 floats = 2.44 MB.
#define OFF_H1PRE 0       // 1024
#define OFF_H2PRE 1024    // 256
#define OFF_ZW    1408    // 256
#define OFF_GW    1664    // 8192
#define OFF_D2H   9856    // 65536
#define OFF_S4    75392   // 8192  (16B aligned)
#define OFF_Y4    83584   // 524288 (16B aligned)
#define OFF_MIN   607872  // 2048 (uint)
#define OFF_ACC   609920  // 1

// ---------------- K0: init + S4 pack + gw precompute ----------------
__global__ __launch_bounds__(256) void k0_init(
    const float* __restrict__ x, const float* __restrict__ grid,
    const float* __restrict__ Wd1,
    float* __restrict__ gw, float* __restrict__ S4,
    float* __restrict__ h1pre, float* __restrict__ h2pre,
    unsigned* __restrict__ minarr, float* __restrict__ accum) {
  int t = blockIdx.x * 256 + threadIdx.x;   // 64 blocks -> 16384 threads
  if (t < 8192) {
    // gw[g][j] = sum_k grid[g][k] * Wd1[64+k][j]
    int g = t >> 7, j = t & 127;
    float a = grid[g * 3 + 0] * Wd1[64 * 128 + j]
            + grid[g * 3 + 1] * Wd1[65 * 128 + j]
            + grid[g * 3 + 2] * Wd1[66 * 128 + j];
    gw[t] = a;
  } else if (t < 10240) {
    int p = t - 8192;                       // b*1024+m
    const float* xp = x + p * 3;
    float s0 = xp[0], s1 = xp[1], s2 = xp[2];
    ((float4*)S4)[p] = make_float4(s0, s1, s2, s0 * s0 + s1 * s1 + s2 * s2);
  } else if (t < 11264) {
    h1pre[t - 10240] = 0.f;
  } else if (t < 11520) {
    h2pre[t - 11264] = 0.f;
  } else if (t < 13568) {
    minarr[t - 11520] = 0x7F800000u;        // +inf
  } else if (t == 13568) {
    accum[0] = 0.f;
  }
}

// ---------------- K1: encoder L1 partial sums (k-split) ----------------
// grid 192 = b(2) x jb(4) x kc(24); 128 threads
__global__ __launch_bounds__(128) void k1_enc1(
    const float* __restrict__ x, const float* __restrict__ We1,
    float* __restrict__ h1pre) {
  int blk = blockIdx.x;
  int kc = blk % 24;
  int jb = (blk / 24) % 4;
  int b  = blk / 96;
  int j = jb * 128 + threadIdx.x;
  const float* xb = x + b * 3072 + kc * 128;   // uniform -> s_load
  const float* W  = We1 + (kc * 128) * 512 + j;
  float acc = 0.f;
#pragma unroll 8
  for (int k = 0; k < 128; ++k) acc += xb[k] * W[k * 512];
  atomicAdd(&h1pre[b * 512 + j], acc);
}

// ---------------- K2: encoder L2 partial sums ----------------
// grid 16 = b(2) x kc(8); 128 threads
__global__ __launch_bounds__(128) void k2_enc2(
    const float* __restrict__ h1pre, const float* __restrict__ be1,
    const float* __restrict__ We2, float* __restrict__ h2pre) {
  int kc = blockIdx.x % 8, b = blockIdx.x / 8;
  int j = threadIdx.x;
  float acc = 0.f;
#pragma unroll 4
  for (int kk = 0; kk < 64; ++kk) {
    int k = kc * 64 + kk;
    float h = fmaxf(h1pre[b * 512 + k] + be1[k], 0.f);  // uniform
    acc += h * We2[k * 128 + j];
  }
  atomicAdd(&h2pre[b * 128 + j], acc);
}

// ---------------- K3: encoder L3 + zw (z @ Wd1[:64] + bd1) ----------------
// 1 block, 128 threads
__global__ __launch_bounds__(128) void k3_enc3_zw(
    const float* __restrict__ h2pre, const float* __restrict__ be2,
    const float* __restrict__ We3, const float* __restrict__ be3,
    const float* __restrict__ Wd1, const float* __restrict__ bd1,
    float* __restrict__ zw) {
  __shared__ float zl[128];                // [b][64]
  int t = threadIdx.x;
  int b = t >> 6, j = t & 63;
  float acc = be3[j];
#pragma unroll 4
  for (int k = 0; k < 128; ++k) {
    float h = fmaxf(h2pre[b * 128 + k] + be2[k], 0.f);
    acc += h * We3[k * 64 + j];
  }
  zl[t] = fmaxf(acc, 0.f);
  __syncthreads();
#pragma unroll
  for (int o = 0; o < 2; ++o) {
    int idx = o * 128 + t;                 // 256 outputs
    int bb = idx >> 7, jj = idx & 127;
    float a2 = bd1[jj];
#pragma unroll 4
    for (int k = 0; k < 64; ++k) a2 += zl[bb * 64 + k] * Wd1[k * 128 + jj];
    zw[idx] = a2;                          // relu applied later with gw
  }
}

// ---------------- K4: decoder L2: d2h[b,g,:512] ----------------
// 128 blocks = (b*64+g); 256 threads, 2 outputs each
__global__ __launch_bounds__(256) void k4_dec2(
    const float* __restrict__ zw, const float* __restrict__ gw,
    const float* __restrict__ Wd2, const float* __restrict__ bd2,
    float* __restrict__ d2h) {
  __shared__ float d1[128];
  int bg = blockIdx.x;
  int b = bg >> 6, g = bg & 63;
  int t = threadIdx.x;
  if (t < 128) d1[t] = fmaxf(zw[b * 128 + t] + gw[g * 128 + t], 0.f);
  __syncthreads();
  float a0 = bd2[t], a1 = bd2[t + 256];
#pragma unroll 4
  for (int k = 0; k < 128; ++k) {
    float dv = d1[k];
    a0 += dv * Wd2[k * 512 + t];
    a1 += dv * Wd2[k * 512 + t + 256];
  }
  float* o = d2h + bg * 512;
  o[t] = fmaxf(a0, 0.f);
  o[t + 256] = fmaxf(a1, 0.f);
}

// ---------------- K5: decoder L3 + tanh + Y4 pack ----------------
// 128 blocks = rg(8) x pg(16); 256 threads; wave handles 4 rows x 64 points
__global__ __launch_bounds__(256) void k5_dec3_y4(
    const float* __restrict__ d2h, const float* __restrict__ Wd3,
    const float* __restrict__ bd3, float* __restrict__ Y4) {
  int rg = blockIdx.x >> 4;
  int pg = blockIdx.x & 15;
  int lane = threadIdx.x & 63;
  int w = __builtin_amdgcn_readfirstlane(threadIdx.x >> 6);  // uniform wave id
  int row0 = rg * 16 + w * 4;              // 4 rows (b*64+g) for this wave
  int p = pg * 64 + lane;                  // point index within g-row
  float b0 = bd3[3 * p], b1 = bd3[3 * p + 1], b2 = bd3[3 * p + 2];
  const float* Wp = Wd3 + 3 * p;
  float acc[4][3] = {};
#pragma unroll 4
  for (int k = 0; k < 512; ++k) {
    float w0 = Wp[k * 3072], w1 = Wp[k * 3072 + 1], w2 = Wp[k * 3072 + 2];
#pragma unroll
    for (int r = 0; r < 4; ++r) {
      float h = d2h[(row0 + r) * 512 + k]; // uniform -> s_load
      acc[r][0] += h * w0;
      acc[r][1] += h * w1;
      acc[r][2] += h * w2;
    }
  }
#pragma unroll
  for (int r = 0; r < 4; ++r) {
    int row = row0 + r;                    // b*64+g
    float y0 = tanhf(acc[r][0] + b0);
    float y1 = tanhf(acc[r][1] + b1);
    float y2 = tanhf(acc[r][2] + b2);
    ((float4*)Y4)[row * 1024 + p] =
        make_float4(y0, y1, y2, y0 * y0 + y1 * y1 + y2 * y2);
  }
}

// ---------------- K6: chamfer dir1: sum_n min_m d2 ----------------
// 512 blocks x 256: thread = (b, n)
__global__ __launch_bounds__(256) void k6_dir1(
    const float4* __restrict__ Y4, const float4* __restrict__ S4,
    float* __restrict__ accum) {
  int t = blockIdx.x * 256 + threadIdx.x;
  int b = t >> 16, n = t & 65535;
  float4 y = Y4[b * 65536 + n];            // per-lane coalesced
  const float4* Sb = S4 + b * 1024;
  float mn0 = __builtin_inff(), mn1 = mn0, mn2 = mn0, mn3 = mn0;
#pragma unroll 2
  for (int m = 0; m < 1024; m += 4) {      // uniform -> s_load
    float4 s0 = Sb[m], s1 = Sb[m + 1], s2 = Sb[m + 2], s3 = Sb[m + 3];
    mn0 = fminf(mn0, __builtin_fmaf(y.x * s0.x + y.y * s0.y + y.z * s0.z, -2.f, s0.w));
    mn1 = fminf(mn1, __builtin_fmaf(y.x * s1.x + y.y * s1.y + y.z * s1.z, -2.f, s1.w));
    mn2 = fminf(mn2, __builtin_fmaf(y.x * s2.x + y.y * s2.y + y.z * s2.z, -2.f, s2.w));
    mn3 = fminf(mn3, __builtin_fmaf(y.x * s3.x + y.y * s3.y + y.z * s3.z, -2.f, s3.w));
  }
  float val = fminf(fminf(mn0, mn1), fminf(mn2, mn3)) + y.w;
  // block-reduce sum, one atomicAdd per block
#pragma unroll
  for (int off = 32; off > 0; off >>= 1) val += __shfl_down(val, off);
  __shared__ float red[4];
  int lane = threadIdx.x & 63, wid = threadIdx.x >> 6;
  if (lane == 0) red[wid] = val;
  __syncthreads();
  if (threadIdx.x == 0)
    atomicAdd(accum, red[0] + red[1] + red[2] + red[3]);
}

// ---------------- K7: chamfer dir2: per-m min over n (chunked) ----------------
// 512 blocks x 256: thread = (b, chunk, m); 64 chunks of 1024 n
__global__ __launch_bounds__(256) void k7_dir2(
    const float4* __restrict__ Y4, const float4* __restrict__ S4,
    unsigned* __restrict__ minarr) {
  int t = blockIdx.x * 256 + threadIdx.x;
  int b = t >> 16, r = t & 65535;
  int m = r & 1023, ch = r >> 10;
  float4 s = S4[b * 1024 + m];             // per-lane coalesced
  const float4* Yc = Y4 + b * 65536 + ch * 1024;
  float mn0 = __builtin_inff(), mn1 = mn0, mn2 = mn0, mn3 = mn0;
#pragma unroll 2
  for (int i = 0; i < 1024; i += 4) {      // uniform -> s_load
    float4 y0 = Yc[i], y1 = Yc[i + 1], y2 = Yc[i + 2], y3 = Yc[i + 3];
    mn0 = fminf(mn0, __builtin_fmaf(s.x * y0.x + s.y * y0.y + s.z * y0.z, -2.f, y0.w));
    mn1 = fminf(mn1, __builtin_fmaf(s.x * y1.x + s.y * y1.y + s.z * y1.z, -2.f, y1.w));
    mn2 = fminf(mn2, __builtin_fmaf(s.x * y2.x + s.y * y2.y + s.z * y2.z, -2.f, y2.w));
    mn3 = fminf(mn3, __builtin_fmaf(s.x * y3.x + s.y * y3.y + s.z * y3.z, -2.f, y3.w));
  }
  float d = fmaxf(fminf(fminf(mn0, mn1), fminf(mn2, mn3)) + s.w, 0.f);
  atomicMin(&minarr[b * 1024 + m], __float_as_uint(d));  // d>=0: uint order ok
}

// ---------------- K8: final reduce ----------------
__global__ __launch_bounds__(256) void k8_final(
    const unsigned* __restrict__ minarr, const float* __restrict__ accum,
    float* __restrict__ out) {
  int t = threadIdx.x;
  float v = 0.f;
#pragma unroll
  for (int i = 0; i < 8; ++i) v += __uint_as_float(minarr[i * 256 + t]);
#pragma unroll
  for (int off = 32; off > 0; off >>= 1) v += __shfl_down(v, off);
  __shared__ float red[4];
  int lane = t & 63, wid = t >> 6;
  if (lane == 0) red[wid] = v;
  __syncthreads();
  if (t == 0) out[0] = red[0] + red[1] + red[2] + red[3] + accum[0];
}

extern "C" void kernel_launch(void* const* d_in, const int* in_sizes, int n_in,
                              void* d_out, int out_size, void* d_ws, size_t ws_size,
                              hipStream_t stream) {
  const float* x   = (const float*)d_in[0];
  const float* grd = (const float*)d_in[1];
  const float* We1 = (const float*)d_in[2];
  const float* be1 = (const float*)d_in[3];
  const float* We2 = (const float*)d_in[4];
  const float* be2 = (const float*)d_in[5];
  const float* We3 = (const float*)d_in[6];
  const float* be3 = (const float*)d_in[7];
  const float* Wd1 = (const float*)d_in[8];
  const float* bd1 = (const float*)d_in[9];
  const float* Wd2 = (const float*)d_in[10];
  const float* bd2 = (const float*)d_in[11];
  const float* Wd3 = (const float*)d_in[12];
  const float* bd3 = (const float*)d_in[13];
  float* ws = (float*)d_ws;
  float* out = (float*)d_out;

  float* h1pre = ws + OFF_H1PRE;
  float* h2pre = ws + OFF_H2PRE;
  float* zw    = ws + OFF_ZW;
  float* gw    = ws + OFF_GW;
  float* d2h   = ws + OFF_D2H;
  float* S4    = ws + OFF_S4;
  float* Y4    = ws + OFF_Y4;
  unsigned* minarr = (unsigned*)(ws + OFF_MIN);
  float* accum = ws + OFF_ACC;

  hipLaunchKernelGGL(k0_init, dim3(64), dim3(256), 0, stream,
                     x, grd, Wd1, gw, S4, h1pre, h2pre, minarr, accum);
  hipLaunchKernelGGL(k1_enc1, dim3(192), dim3(128), 0, stream, x, We1, h1pre);
  hipLaunchKernelGGL(k2_enc2, dim3(16), dim3(128), 0, stream,
                     h1pre, be1, We2, h2pre);
  hipLaunchKernelGGL(k3_enc3_zw, dim3(1), dim3(128), 0, stream,
                     h2pre, be2, We3, be3, Wd1, bd1, zw);
  hipLaunchKernelGGL(k4_dec2, dim3(128), dim3(256), 0, stream,
                     zw, gw, Wd2, bd2, d2h);
  hipLaunchKernelGGL(k5_dec3_y4, dim3(128), dim3(256), 0, stream,
                     d2h, Wd3, bd3, Y4);
  hipLaunchKernelGGL(k6_dir1, dim3(512), dim3(256), 0, stream,
                     (const float4*)Y4, (const float4*)S4, accum);
  hipLaunchKernelGGL(k7_dir2, dim3(512), dim3(256), 0, stream,
                     (const float4*)Y4, (const float4*)S4, minarr);
  hipLaunchKernelGGL(k8_final, dim3(1), dim3(256), 0, stream,
                     minarr, accum, out);
}

// Round 2
// 239.562 us; speedup vs baseline: 1.2863x; 1.2863x over previous
//
#include <hip/hip_runtime.h>

// Problem constants
#define NB 2        // batch
#define NPTS 1024   // D_IN points per cloud
#define NGEN 65536  // G * D_IN generated points
#define NG 64       // grid points

// ws layout (float offsets).
#define OFF_H1PRE 0       // 1024
#define OFF_H2PRE 1024    // 256
#define OFF_ZW    1408    // 256
#define OFF_GW    1664    // 8192
#define OFF_D2H   9856    // 65536
#define OFF_S4    75392   // 8192   (16B aligned)
#define OFF_Y4    83584   // 524288 (16B aligned)
#define OFF_MPART 607872  // 131072 (dir2 partial mins: [b][64 chunks][1024 m])
// total 738944 floats = 2.96 MB

// ---------------- K0: init + S4 pack + gw precompute + out zero ----------------
__global__ __launch_bounds__(256) void k0_init(
    const float* __restrict__ x, const float* __restrict__ grid,
    const float* __restrict__ Wd1,
    float* __restrict__ gw, float* __restrict__ S4,
    float* __restrict__ h1pre, float* __restrict__ h2pre,
    float* __restrict__ out) {
  int t = blockIdx.x * 256 + threadIdx.x;   // 64 blocks -> 16384 threads
  if (t < 8192) {
    // gw[g][j] = sum_k grid[g][k] * Wd1[64+k][j]
    int g = t >> 7, j = t & 127;
    float a = grid[g * 3 + 0] * Wd1[64 * 128 + j]
            + grid[g * 3 + 1] * Wd1[65 * 128 + j]
            + grid[g * 3 + 2] * Wd1[66 * 128 + j];
    gw[t] = a;
  } else if (t < 10240) {
    int p = t - 8192;                       // b*1024+m
    const float* xp = x + p * 3;
    float s0 = xp[0], s1 = xp[1], s2 = xp[2];
    ((float4*)S4)[p] = make_float4(s0, s1, s2, s0 * s0 + s1 * s1 + s2 * s2);
  } else if (t < 11264) {
    h1pre[t - 10240] = 0.f;
  } else if (t < 11520) {
    h2pre[t - 11264] = 0.f;
  } else if (t == 11520) {
    out[0] = 0.f;
  }
}

// ---------------- K1: encoder L1 partial sums (k-split) ----------------
// grid 192 = b(2) x jb(4) x kc(24); 128 threads
__global__ __launch_bounds__(128) void k1_enc1(
    const float* __restrict__ x, const float* __restrict__ We1,
    float* __restrict__ h1pre) {
  int blk = blockIdx.x;
  int kc = blk % 24;
  int jb = (blk / 24) % 4;
  int b  = blk / 96;
  int j = jb * 128 + threadIdx.x;
  const float* xb = x + b * 3072 + kc * 128;   // uniform -> s_load
  const float* W  = We1 + (kc * 128) * 512 + j;
  float acc = 0.f;
#pragma unroll 8
  for (int k = 0; k < 128; ++k) acc += xb[k] * W[k * 512];
  atomicAdd(&h1pre[b * 512 + j], acc);
}

// ---------------- K2: encoder L2 partial sums ----------------
// grid 16 = b(2) x kc(8); 128 threads
__global__ __launch_bounds__(128) void k2_enc2(
    const float* __restrict__ h1pre, const float* __restrict__ be1,
    const float* __restrict__ We2, float* __restrict__ h2pre) {
  int kc = blockIdx.x % 8, b = blockIdx.x / 8;
  int j = threadIdx.x;
  float acc = 0.f;
#pragma unroll 4
  for (int kk = 0; kk < 64; ++kk) {
    int k = kc * 64 + kk;
    float h = fmaxf(h1pre[b * 512 + k] + be1[k], 0.f);  // uniform
    acc += h * We2[k * 128 + j];
  }
  atomicAdd(&h2pre[b * 128 + j], acc);
}

// ---------------- K3: encoder L3 + zw (z @ Wd1[:64] + bd1) ----------------
// 1 block, 128 threads
__global__ __launch_bounds__(128) void k3_enc3_zw(
    const float* __restrict__ h2pre, const float* __restrict__ be2,
    const float* __restrict__ We3, const float* __restrict__ be3,
    const float* __restrict__ Wd1, const float* __restrict__ bd1,
    float* __restrict__ zw) {
  __shared__ float zl[128];                // [b][64]
  int t = threadIdx.x;
  int b = t >> 6, j = t & 63;
  float acc = be3[j];
#pragma unroll 4
  for (int k = 0; k < 128; ++k) {
    float h = fmaxf(h2pre[b * 128 + k] + be2[k], 0.f);
    acc += h * We3[k * 64 + j];
  }
  zl[t] = fmaxf(acc, 0.f);
  __syncthreads();
#pragma unroll
  for (int o = 0; o < 2; ++o) {
    int idx = o * 128 + t;                 // 256 outputs
    int bb = idx >> 7, jj = idx & 127;
    float a2 = bd1[jj];
#pragma unroll 4
    for (int k = 0; k < 64; ++k) a2 += zl[bb * 64 + k] * Wd1[k * 128 + jj];
    zw[idx] = a2;                          // relu applied later with gw
  }
}

// ---------------- K4: decoder L2: d2h[b,g,:512] ----------------
// 128 blocks = (b*64+g); 256 threads, 2 outputs each
__global__ __launch_bounds__(256) void k4_dec2(
    const float* __restrict__ zw, const float* __restrict__ gw,
    const float* __restrict__ Wd2, const float* __restrict__ bd2,
    float* __restrict__ d2h) {
  __shared__ float d1[128];
  int bg = blockIdx.x;
  int b = bg >> 6, g = bg & 63;
  int t = threadIdx.x;
  if (t < 128) d1[t] = fmaxf(zw[b * 128 + t] + gw[g * 128 + t], 0.f);
  __syncthreads();
  float a0 = bd2[t], a1 = bd2[t + 256];
#pragma unroll 4
  for (int k = 0; k < 128; ++k) {
    float dv = d1[k];
    a0 += dv * Wd2[k * 512 + t];
    a1 += dv * Wd2[k * 512 + t + 256];
  }
  float* o = d2h + bg * 512;
  o[t] = fmaxf(a0, 0.f);
  o[t + 256] = fmaxf(a1, 0.f);
}

// ---------------- K5: decoder L3 + tanh + Y4 pack (LDS-staged) ----------------
// 256 blocks = rt(16 row-tiles of 8) x pg(16 p-groups of 64); 256 threads.
// Wave w handles 2 rows; lane = p within group. Per k-iter: 12B Wd3 load
// (shared across the 4 waves via L1) + 2 LDS broadcasts + 6 FMA.
__global__ __launch_bounds__(256) void k5_dec3_y4(
    const float* __restrict__ d2h, const float* __restrict__ Wd3,
    const float* __restrict__ bd3, float* __restrict__ Y4) {
  __shared__ float a_lds[8 * 512];         // 8 rows x 512 k = 16 KB
  int rt = blockIdx.x >> 4;
  int pg = blockIdx.x & 15;
  int t = threadIdx.x;
  // stage 8 rows of d2h (coalesced float4)
  {
    const float4* src = (const float4*)d2h + rt * 1024;
    float4* dst = (float4*)a_lds;
#pragma unroll
    for (int i = 0; i < 4; ++i) dst[i * 256 + t] = src[i * 256 + t];
  }
  __syncthreads();
  int lane = t & 63;
  int w = t >> 6;
  int r0 = w * 2, r1 = w * 2 + 1;          // local rows
  int p = pg * 64 + lane;                  // point index 0..1023
  const float* wp = Wd3 + p * 3;
  float acc00 = 0.f, acc01 = 0.f, acc02 = 0.f;
  float acc10 = 0.f, acc11 = 0.f, acc12 = 0.f;
#pragma unroll 4
  for (int k = 0; k < 512; ++k) {
    float w0 = wp[k * 3072 + 0];
    float w1 = wp[k * 3072 + 1];
    float w2 = wp[k * 3072 + 2];
    float a0 = a_lds[r0 * 512 + k];        // wave-uniform broadcast
    float a1 = a_lds[r1 * 512 + k];
    acc00 = __builtin_fmaf(a0, w0, acc00);
    acc01 = __builtin_fmaf(a0, w1, acc01);
    acc02 = __builtin_fmaf(a0, w2, acc02);
    acc10 = __builtin_fmaf(a1, w0, acc10);
    acc11 = __builtin_fmaf(a1, w1, acc11);
    acc12 = __builtin_fmaf(a1, w2, acc12);
  }
  float b0 = bd3[3 * p], b1 = bd3[3 * p + 1], b2 = bd3[3 * p + 2];
  {
    int row = rt * 8 + r0;
    float y0 = tanhf(acc00 + b0), y1 = tanhf(acc01 + b1), y2 = tanhf(acc02 + b2);
    ((float4*)Y4)[row * 1024 + p] =
        make_float4(y0, y1, y2, y0 * y0 + y1 * y1 + y2 * y2);
  }
  {
    int row = rt * 8 + r1;
    float y0 = tanhf(acc10 + b0), y1 = tanhf(acc11 + b1), y2 = tanhf(acc12 + b2);
    ((float4*)Y4)[row * 1024 + p] =
        make_float4(y0, y1, y2, y0 * y0 + y1 * y1 + y2 * y2);
  }
}

// ---------------- K6: chamfer dir1: sum_n min_m d2 (LDS + 4-y register tile) --
// 512 blocks = b(2) x nt(256 n-tiles of 256); 256 threads = 4 waves.
// Wave w covers m-quarter [w*256,(w+1)*256); thread holds 4 y's (n = r*64+lane).
__global__ __launch_bounds__(256) void k6_dir1(
    const float4* __restrict__ Y4, const float4* __restrict__ S4,
    float* __restrict__ out) {
  __shared__ float4 s_lds[1024];           // 16 KB
  __shared__ float red[1024];              // 4 KB: [w][slot]
  int b = blockIdx.x >> 8;
  int nt = blockIdx.x & 255;
  int t = threadIdx.x;
  {
    const float4* src = S4 + b * 1024;
#pragma unroll
    for (int i = 0; i < 4; ++i) s_lds[i * 256 + t] = src[i * 256 + t];
  }
  int lane = t & 63, w = t >> 6;
  int nbase = nt * 256;
  float4 y0 = Y4[b * 65536 + nbase + 0 * 64 + lane];
  float4 y1 = Y4[b * 65536 + nbase + 1 * 64 + lane];
  float4 y2 = Y4[b * 65536 + nbase + 2 * 64 + lane];
  float4 y3 = Y4[b * 65536 + nbase + 3 * 64 + lane];
  __syncthreads();
  float mn0 = __builtin_inff(), mn1 = mn0, mn2 = mn0, mn3 = mn0;
  const float4* sq = s_lds + w * 256;
#pragma unroll 4
  for (int mm = 0; mm < 256; ++mm) {
    float4 s = sq[mm];                     // wave-uniform broadcast (no conflict)
    float d0 = __builtin_fmaf(y0.x * s.x + y0.y * s.y + y0.z * s.z, -2.f, s.w);
    float d1 = __builtin_fmaf(y1.x * s.x + y1.y * s.y + y1.z * s.z, -2.f, s.w);
    float d2 = __builtin_fmaf(y2.x * s.x + y2.y * s.y + y2.z * s.z, -2.f, s.w);
    float d3 = __builtin_fmaf(y3.x * s.x + y3.y * s.y + y3.z * s.z, -2.f, s.w);
    mn0 = fminf(mn0, d0); mn1 = fminf(mn1, d1);
    mn2 = fminf(mn2, d2); mn3 = fminf(mn3, d3);
  }
  red[w * 256 + 0 * 64 + lane] = mn0 + y0.w;
  red[w * 256 + 1 * 64 + lane] = mn1 + y1.w;
  red[w * 256 + 2 * 64 + lane] = mn2 + y2.w;
  red[w * 256 + 3 * 64 + lane] = mn3 + y3.w;
  __syncthreads();
  // per-n min over the 4 m-quarters, then block sum -> 1 atomic
  float v = fminf(fminf(red[t], red[256 + t]), fminf(red[512 + t], red[768 + t]));
#pragma unroll
  for (int off = 32; off > 0; off >>= 1) v += __shfl_down(v, off);
  __shared__ float bsum[4];
  if (lane == 0) bsum[w] = v;
  __syncthreads();
  if (t == 0) atomicAdd(out, bsum[0] + bsum[1] + bsum[2] + bsum[3]);
}

// ---------------- K7: chamfer dir2: per-m partial min over n-chunk ----------
// 512 blocks = b(2) x mg(4 m-groups of 256) x nch(64 n-chunks of 1024).
// Thread holds 4 s-points; wave w covers n sub-quarter. No atomics: store
// partial min to mpart[b][nch][m].
__global__ __launch_bounds__(256) void k7_dir2(
    const float4* __restrict__ Y4, const float4* __restrict__ S4,
    float* __restrict__ mpart) {
  __shared__ float4 y_lds[1024];           // 16 KB
  __shared__ float red[1024];
  int b = blockIdx.x >> 8;
  int mg = (blockIdx.x >> 6) & 3;
  int nch = blockIdx.x & 63;
  int t = threadIdx.x;
  {
    const float4* src = Y4 + b * 65536 + nch * 1024;
#pragma unroll
    for (int i = 0; i < 4; ++i) y_lds[i * 256 + t] = src[i * 256 + t];
  }
  int lane = t & 63, w = t >> 6;
  float4 s0 = S4[b * 1024 + mg * 256 + 0 * 64 + lane];
  float4 s1 = S4[b * 1024 + mg * 256 + 1 * 64 + lane];
  float4 s2 = S4[b * 1024 + mg * 256 + 2 * 64 + lane];
  float4 s3 = S4[b * 1024 + mg * 256 + 3 * 64 + lane];
  __syncthreads();
  float mn0 = __builtin_inff(), mn1 = mn0, mn2 = mn0, mn3 = mn0;
  const float4* yq = y_lds + w * 256;
#pragma unroll 4
  for (int nn = 0; nn < 256; ++nn) {
    float4 y = yq[nn];                     // wave-uniform broadcast
    float d0 = __builtin_fmaf(s0.x * y.x + s0.y * y.y + s0.z * y.z, -2.f, y.w);
    float d1 = __builtin_fmaf(s1.x * y.x + s1.y * y.y + s1.z * y.z, -2.f, y.w);
    float d2 = __builtin_fmaf(s2.x * y.x + s2.y * y.y + s2.z * y.z, -2.f, y.w);
    float d3 = __builtin_fmaf(s3.x * y.x + s3.y * y.y + s3.z * y.z, -2.f, y.w);
    mn0 = fminf(mn0, d0); mn1 = fminf(mn1, d1);
    mn2 = fminf(mn2, d2); mn3 = fminf(mn3, d3);
  }
  red[w * 256 + 0 * 64 + lane] = mn0 + s0.w;
  red[w * 256 + 1 * 64 + lane] = mn1 + s1.w;
  red[w * 256 + 2 * 64 + lane] = mn2 + s2.w;
  red[w * 256 + 3 * 64 + lane] = mn3 + s3.w;
  __syncthreads();
  float v = fminf(fminf(red[t], red[256 + t]), fminf(red[512 + t], red[768 + t]));
  mpart[(b * 64 + nch) * 1024 + mg * 256 + t] = v;   // coalesced store
}

// ---------------- K8: dir2 final reduce: min over 64 chunks, sum, atomicAdd --
// 8 blocks x 256 threads; thread = one (b,m).
__global__ __launch_bounds__(256) void k8_dir2_reduce(
    const float* __restrict__ mpart, float* __restrict__ out) {
  int gid = blockIdx.x * 256 + threadIdx.x;   // 0..2047
  int b = gid >> 10, m = gid & 1023;
  float v = __builtin_inff();
#pragma unroll 4
  for (int ch = 0; ch < 64; ++ch)
    v = fminf(v, mpart[(b * 64 + ch) * 1024 + m]);  // coalesced (lane = m)
#pragma unroll
  for (int off = 32; off > 0; off >>= 1) v += __shfl_down(v, off);
  __shared__ float bsum[4];
  int lane = threadIdx.x & 63, w = threadIdx.x >> 6;
  if (lane == 0) bsum[w] = v;
  __syncthreads();
  if (threadIdx.x == 0) atomicAdd(out, bsum[0] + bsum[1] + bsum[2] + bsum[3]);
}

extern "C" void kernel_launch(void* const* d_in, const int* in_sizes, int n_in,
                              void* d_out, int out_size, void* d_ws, size_t ws_size,
                              hipStream_t stream) {
  const float* x   = (const float*)d_in[0];
  const float* grd = (const float*)d_in[1];
  const float* We1 = (const float*)d_in[2];
  const float* be1 = (const float*)d_in[3];
  const float* We2 = (const float*)d_in[4];
  const float* be2 = (const float*)d_in[5];
  const float* We3 = (const float*)d_in[6];
  const float* be3 = (const float*)d_in[7];
  const float* Wd1 = (const float*)d_in[8];
  const float* bd1 = (const float*)d_in[9];
  const float* Wd2 = (const float*)d_in[10];
  const float* bd2 = (const float*)d_in[11];
  const float* Wd3 = (const float*)d_in[12];
  const float* bd3 = (const float*)d_in[13];
  float* ws = (float*)d_ws;
  float* out = (float*)d_out;

  float* h1pre = ws + OFF_H1PRE;
  float* h2pre = ws + OFF_H2PRE;
  float* zw    = ws + OFF_ZW;
  float* gw    = ws + OFF_GW;
  float* d2h   = ws + OFF_D2H;
  float* S4    = ws + OFF_S4;
  float* Y4    = ws + OFF_Y4;
  float* mpart = ws + OFF_MPART;

  hipLaunchKernelGGL(k0_init, dim3(64), dim3(256), 0, stream,
                     x, grd, Wd1, gw, S4, h1pre, h2pre, out);
  hipLaunchKernelGGL(k1_enc1, dim3(192), dim3(128), 0, stream, x, We1, h1pre);
  hipLaunchKernelGGL(k2_enc2, dim3(16), dim3(128), 0, stream,
                     h1pre, be1, We2, h2pre);
  hipLaunchKernelGGL(k3_enc3_zw, dim3(1), dim3(128), 0, stream,
                     h2pre, be2, We3, be3, Wd1, bd1, zw);
  hipLaunchKernelGGL(k4_dec2, dim3(128), dim3(256), 0, stream,
                     zw, gw, Wd2, bd2, d2h);
  hipLaunchKernelGGL(k5_dec3_y4, dim3(256), dim3(256), 0, stream,
                     d2h, Wd3, bd3, Y4);
  hipLaunchKernelGGL(k6_dir1, dim3(512), dim3(256), 0, stream,
                     (const float4*)Y4, (const float4*)S4, out);
  hipLaunchKernelGGL(k7_dir2, dim3(512), dim3(256), 0, stream,
                     (const float4*)Y4, (const float4*)S4, mpart);
  hipLaunchKernelGGL(k8_dir2_reduce, dim3(8), dim3(256), 0, stream,
                     mpart, out);
}

// Round 3
// 196.626 us; speedup vs baseline: 1.5671x; 1.2184x over previous
//
#include <hip/hip_runtime.h>

// Problem constants
#define NB 2        // batch
#define NPTS 1024   // points per cloud
#define NGEN 65536  // G * D_IN generated points per batch

// ws layout (float offsets), all 16B-aligned where accessed as float4.
#define OFF_H1PRE 0        // 1024
#define OFF_H2PRE 1024     // 256
#define OFF_ZW    1280     // 256
#define OFF_GW    1536     // 8192
#define OFF_D2H   9728     // 65536
#define OFF_S4    75264    // 8192
#define OFF_Y4    83456    // 524288
#define OFF_WT4   607744   // 1572864 (3*128*1024 float4)
#define OFF_MPART 2180608  // 131072
// total 2311680 floats = 9.25 MB

// ---------------- K0: init + S4 pack + gw + Wd3 transpose ----------------
// blocks 0..63: init work; blocks 64..1599: transpose Wd3 -> Wt4[c][k4][p]
__global__ __launch_bounds__(256) void k0_init_t(
    const float* __restrict__ x, const float* __restrict__ grid,
    const float* __restrict__ Wd1, const float* __restrict__ Wd3,
    float* __restrict__ gw, float* __restrict__ S4,
    float* __restrict__ h1pre, float* __restrict__ h2pre,
    float4* __restrict__ Wt4, float* __restrict__ out) {
  if (blockIdx.x < 64) {
    int t = blockIdx.x * 256 + threadIdx.x;
    if (t < 8192) {
      int g = t >> 7, j = t & 127;
      float a = grid[g * 3 + 0] * Wd1[64 * 128 + j]
              + grid[g * 3 + 1] * Wd1[65 * 128 + j]
              + grid[g * 3 + 2] * Wd1[66 * 128 + j];
      gw[t] = a;
    } else if (t < 10240) {
      int p = t - 8192;
      const float* xp = x + p * 3;
      float s0 = xp[0], s1 = xp[1], s2 = xp[2];
      ((float4*)S4)[p] = make_float4(s0, s1, s2, s0 * s0 + s1 * s1 + s2 * s2);
    } else if (t < 11264) {
      h1pre[t - 10240] = 0.f;
    } else if (t < 11520) {
      h2pre[t - 11264] = 0.f;
    } else if (t == 11520) {
      out[0] = 0.f;
    }
  } else {
    int tid = (blockIdx.x - 64) * 256 + threadIdx.x;  // 0..393215
    int p  = tid & 1023;
    int k4 = (tid >> 10) & 127;
    int c  = tid >> 17;                               // 0..2
    const float* W = Wd3 + (k4 * 4) * 3072 + p * 3 + c;
    float w0 = W[0], w1 = W[3072], w2 = W[2 * 3072], w3 = W[3 * 3072];
    Wt4[(c * 128 + k4) * 1024 + p] = make_float4(w0, w1, w2, w3);
  }
}

// ---------------- K1: encoder L1 partial sums (k-split) ----------------
__global__ __launch_bounds__(128) void k1_enc1(
    const float* __restrict__ x, const float* __restrict__ We1,
    float* __restrict__ h1pre) {
  int blk = blockIdx.x;
  int kc = blk % 24;
  int jb = (blk / 24) % 4;
  int b  = blk / 96;
  int j = jb * 128 + threadIdx.x;
  const float* xb = x + b * 3072 + kc * 128;   // uniform -> s_load
  const float* W  = We1 + (kc * 128) * 512 + j;
  float acc = 0.f;
#pragma unroll 8
  for (int k = 0; k < 128; ++k) acc += xb[k] * W[k * 512];
  atomicAdd(&h1pre[b * 512 + j], acc);
}

// ---------------- K2: encoder L2 partial sums ----------------
__global__ __launch_bounds__(128) void k2_enc2(
    const float* __restrict__ h1pre, const float* __restrict__ be1,
    const float* __restrict__ We2, float* __restrict__ h2pre) {
  int kc = blockIdx.x % 8, b = blockIdx.x / 8;
  int j = threadIdx.x;
  float acc = 0.f;
#pragma unroll 4
  for (int kk = 0; kk < 64; ++kk) {
    int k = kc * 64 + kk;
    float h = fmaxf(h1pre[b * 512 + k] + be1[k], 0.f);
    acc += h * We2[k * 128 + j];
  }
  atomicAdd(&h2pre[b * 128 + j], acc);
}

// ---------------- K3: encoder L3 + zw ----------------
__global__ __launch_bounds__(128) void k3_enc3_zw(
    const float* __restrict__ h2pre, const float* __restrict__ be2,
    const float* __restrict__ We3, const float* __restrict__ be3,
    const float* __restrict__ Wd1, const float* __restrict__ bd1,
    float* __restrict__ zw) {
  __shared__ float zl[128];
  int t = threadIdx.x;
  int b = t >> 6, j = t & 63;
  float acc = be3[j];
#pragma unroll 4
  for (int k = 0; k < 128; ++k) {
    float h = fmaxf(h2pre[b * 128 + k] + be2[k], 0.f);
    acc += h * We3[k * 64 + j];
  }
  zl[t] = fmaxf(acc, 0.f);
  __syncthreads();
#pragma unroll
  for (int o = 0; o < 2; ++o) {
    int idx = o * 128 + t;
    int bb = idx >> 7, jj = idx & 127;
    float a2 = bd1[jj];
#pragma unroll 4
    for (int k = 0; k < 64; ++k) a2 += zl[bb * 64 + k] * Wd1[k * 128 + jj];
    zw[idx] = a2;
  }
}

// ---------------- K4: decoder L2 ----------------
__global__ __launch_bounds__(256) void k4_dec2(
    const float* __restrict__ zw, const float* __restrict__ gw,
    const float* __restrict__ Wd2, const float* __restrict__ bd2,
    float* __restrict__ d2h) {
  __shared__ float d1[128];
  int bg = blockIdx.x;
  int b = bg >> 6, g = bg & 63;
  int t = threadIdx.x;
  if (t < 128) d1[t] = fmaxf(zw[b * 128 + t] + gw[g * 128 + t], 0.f);
  __syncthreads();
  float a0 = bd2[t], a1 = bd2[t + 256];
#pragma unroll 4
  for (int k = 0; k < 128; ++k) {
    float dv = d1[k];
    a0 += dv * Wd2[k * 512 + t];
    a1 += dv * Wd2[k * 512 + t + 256];
  }
  float* o = d2h + bg * 512;
  o[t] = fmaxf(a0, 0.f);
  o[t + 256] = fmaxf(a1, 0.f);
}

// ---------------- K5: decoder L3 + tanh + (-2y, |y|^2) pack ----------------
// 256 blocks = rt(16 row-tiles of 8) x pg(16); 256 threads (4 waves).
// Wave w: rows {2w, 2w+1}; lane = p in group. Inner: per 4-k step, 3 coalesced
// dwordx4 Wt4 loads + 2 LDS b128 broadcasts + 24 FMA.
__global__ __launch_bounds__(256) void k5_dec3_y4(
    const float* __restrict__ d2h, const float4* __restrict__ Wt4,
    const float* __restrict__ bd3, float4* __restrict__ Y4) {
  __shared__ float4 a_lds[8 * 128];        // 8 rows x 512 k = 16 KB
  int rt = blockIdx.x >> 4;
  int pg = blockIdx.x & 15;
  int t = threadIdx.x;
  {
    const float4* src = (const float4*)d2h + rt * 1024;
#pragma unroll
    for (int i = 0; i < 4; ++i) a_lds[i * 256 + t] = src[i * 256 + t];
  }
  __syncthreads();
  int lane = t & 63, w = t >> 6;
  int r0 = w * 2, r1 = w * 2 + 1;
  int p = pg * 64 + lane;
  const float4* wp0 = Wt4 + p;             // c=0
  const float4* wp1 = Wt4 + 131072 + p;    // c=1
  const float4* wp2 = Wt4 + 262144 + p;    // c=2
  float a00 = 0.f, a01 = 0.f, a02 = 0.f;
  float a10 = 0.f, a11 = 0.f, a12 = 0.f;
#pragma unroll 4
  for (int k4 = 0; k4 < 128; ++k4) {
    float4 A0 = a_lds[r0 * 128 + k4];      // wave-uniform broadcast
    float4 A1 = a_lds[r1 * 128 + k4];
    float4 w0 = wp0[k4 * 1024];
    float4 w1 = wp1[k4 * 1024];
    float4 w2 = wp2[k4 * 1024];
    a00 += A0.x * w0.x + A0.y * w0.y + A0.z * w0.z + A0.w * w0.w;
    a01 += A0.x * w1.x + A0.y * w1.y + A0.z * w1.z + A0.w * w1.w;
    a02 += A0.x * w2.x + A0.y * w2.y + A0.z * w2.z + A0.w * w2.w;
    a10 += A1.x * w0.x + A1.y * w0.y + A1.z * w0.z + A1.w * w0.w;
    a11 += A1.x * w1.x + A1.y * w1.y + A1.z * w1.z + A1.w * w1.w;
    a12 += A1.x * w2.x + A1.y * w2.y + A1.z * w2.z + A1.w * w2.w;
  }
  float b0 = bd3[p * 3], b1 = bd3[p * 3 + 1], b2 = bd3[p * 3 + 2];
  {
    int row = rt * 8 + r0;
    float y0 = tanhf(a00 + b0), y1 = tanhf(a01 + b1), y2 = tanhf(a02 + b2);
    Y4[row * 1024 + p] = make_float4(-2.f * y0, -2.f * y1, -2.f * y2,
                                     y0 * y0 + y1 * y1 + y2 * y2);
  }
  {
    int row = rt * 8 + r1;
    float y0 = tanhf(a10 + b0), y1 = tanhf(a11 + b1), y2 = tanhf(a12 + b2);
    Y4[row * 1024 + p] = make_float4(-2.f * y0, -2.f * y1, -2.f * y2,
                                     y0 * y0 + y1 * y1 + y2 * y2);
  }
}

// ---------------- K67: merged chamfer, 4 insts/pair ----------------
// blocks 0..255: dir1 (sum_n min_m), blocks 256..511: dir2 partial mins.
// Exactly 2048 waves = 2 waves/SIMD.
__global__ __launch_bounds__(256) void k67_chamfer(
    const float4* __restrict__ Y4, const float4* __restrict__ S4,
    float* __restrict__ mpart, float* __restrict__ out) {
  __shared__ float4 c_lds[1024];           // 16 KB inner cloud
  int t = threadIdx.x;
  if (blockIdx.x < 256) {
    // ---- dir1: resident my = (-2y, |y|^2); LDS = S (plain, |s|^2) ----
    int b = blockIdx.x >> 7, nt = blockIdx.x & 127;
    {
      const float4* src = S4 + b * 1024;
#pragma unroll
      for (int i = 0; i < 4; ++i) c_lds[i * 256 + t] = src[i * 256 + t];
    }
    float4 my0 = Y4[b * 65536 + nt * 512 + t];
    float4 my1 = Y4[b * 65536 + nt * 512 + 256 + t];
    __syncthreads();
    float mn0 = __builtin_inff(), mn1 = mn0;
#pragma unroll 8
    for (int m = 0; m < 1024; ++m) {
      float4 s = c_lds[m];                 // block-uniform broadcast
      float d0 = __builtin_fmaf(s.x, my0.x,
                 __builtin_fmaf(s.y, my0.y,
                 __builtin_fmaf(s.z, my0.z, s.w)));
      float d1 = __builtin_fmaf(s.x, my1.x,
                 __builtin_fmaf(s.y, my1.y,
                 __builtin_fmaf(s.z, my1.z, s.w)));
      mn0 = fminf(mn0, d0);
      mn1 = fminf(mn1, d1);
    }
    float v = (mn0 + my0.w) + (mn1 + my1.w);
#pragma unroll
    for (int off = 32; off > 0; off >>= 1) v += __shfl_down(v, off);
    __shared__ float bsum[4];
    int lane = t & 63, w = t >> 6;
    if (lane == 0) bsum[w] = v;
    __syncthreads();
    if (t == 0) atomicAdd(out, bsum[0] + bsum[1] + bsum[2] + bsum[3]);
  } else {
    // ---- dir2: resident s (plain); LDS = Y' = (-2y, |y|^2) ----
    int blk = blockIdx.x - 256;            // 0..255
    int b   = blk >> 7;
    int mg  = (blk >> 6) & 1;
    int nch = blk & 63;
    {
      const float4* src = Y4 + b * 65536 + nch * 1024;
#pragma unroll
      for (int i = 0; i < 4; ++i) c_lds[i * 256 + t] = src[i * 256 + t];
    }
    float4 s0 = S4[b * 1024 + mg * 512 + t];
    float4 s1 = S4[b * 1024 + mg * 512 + 256 + t];
    __syncthreads();
    float mn0 = __builtin_inff(), mn1 = mn0;
#pragma unroll 8
    for (int n = 0; n < 1024; ++n) {
      float4 y = c_lds[n];
      float d0 = __builtin_fmaf(y.x, s0.x,
                 __builtin_fmaf(y.y, s0.y,
                 __builtin_fmaf(y.z, s0.z, y.w)));
      float d1 = __builtin_fmaf(y.x, s1.x,
                 __builtin_fmaf(y.y, s1.y,
                 __builtin_fmaf(y.z, s1.z, y.w)));
      mn0 = fminf(mn0, d0);
      mn1 = fminf(mn1, d1);
    }
    int base = (nch * 2 + b) * 1024 + mg * 512;
    mpart[base + t]       = mn0 + s0.w;
    mpart[base + 256 + t] = mn1 + s1.w;
  }
}

// ---------------- K8: dir2 final reduce ----------------
// 8 blocks x 256; thread = one (b,m); min over 64 chunks then sum.
__global__ __launch_bounds__(256) void k8_dir2_reduce(
    const float* __restrict__ mpart, float* __restrict__ out) {
  int gid = blockIdx.x * 256 + threadIdx.x;   // 0..2047
  int b = gid >> 10, m = gid & 1023;
  float v = __builtin_inff();
#pragma unroll 8
  for (int ch = 0; ch < 64; ++ch)
    v = fminf(v, mpart[(ch * 2 + b) * 1024 + m]);  // coalesced over m
#pragma unroll
  for (int off = 32; off > 0; off >>= 1) v += __shfl_down(v, off);
  __shared__ float bsum[4];
  int lane = threadIdx.x & 63, w = threadIdx.x >> 6;
  if (lane == 0) bsum[w] = v;
  __syncthreads();
  if (threadIdx.x == 0) atomicAdd(out, bsum[0] + bsum[1] + bsum[2] + bsum[3]);
}

extern "C" void kernel_launch(void* const* d_in, const int* in_sizes, int n_in,
                              void* d_out, int out_size, void* d_ws, size_t ws_size,
                              hipStream_t stream) {
  const float* x   = (const float*)d_in[0];
  const float* grd = (const float*)d_in[1];
  const float* We1 = (const float*)d_in[2];
  const float* be1 = (const float*)d_in[3];
  const float* We2 = (const float*)d_in[4];
  const float* be2 = (const float*)d_in[5];
  const float* We3 = (const float*)d_in[6];
  const float* be3 = (const float*)d_in[7];
  const float* Wd1 = (const float*)d_in[8];
  const float* bd1 = (const float*)d_in[9];
  const float* Wd2 = (const float*)d_in[10];
  const float* bd2 = (const float*)d_in[11];
  const float* Wd3 = (const float*)d_in[12];
  const float* bd3 = (const float*)d_in[13];
  float* ws = (float*)d_ws;
  float* out = (float*)d_out;

  float* h1pre = ws + OFF_H1PRE;
  float* h2pre = ws + OFF_H2PRE;
  float* zw    = ws + OFF_ZW;
  float* gw    = ws + OFF_GW;
  float* d2h   = ws + OFF_D2H;
  float* S4    = ws + OFF_S4;
  float* Y4    = ws + OFF_Y4;
  float4* Wt4  = (float4*)(ws + OFF_WT4);
  float* mpart = ws + OFF_MPART;

  hipLaunchKernelGGL(k0_init_t, dim3(1600), dim3(256), 0, stream,
                     x, grd, Wd1, Wd3, gw, S4, h1pre, h2pre, Wt4, out);
  hipLaunchKernelGGL(k1_enc1, dim3(192), dim3(128), 0, stream, x, We1, h1pre);
  hipLaunchKernelGGL(k2_enc2, dim3(16), dim3(128), 0, stream,
                     h1pre, be1, We2, h2pre);
  hipLaunchKernelGGL(k3_enc3_zw, dim3(1), dim3(128), 0, stream,
                     h2pre, be2, We3, be3, Wd1, bd1, zw);
  hipLaunchKernelGGL(k4_dec2, dim3(128), dim3(256), 0, stream,
                     zw, gw, Wd2, bd2, d2h);
  hipLaunchKernelGGL(k5_dec3_y4, dim3(256), dim3(256), 0, stream,
                     d2h, Wt4, bd3, (float4*)Y4);
  hipLaunchKernelGGL(k67_chamfer, dim3(512), dim3(256), 0, stream,
                     (const float4*)Y4, (const float4*)S4, mpart, out);
  hipLaunchKernelGGL(k8_dir2_reduce, dim3(8), dim3(256), 0, stream,
                     mpart, out);
}